// Round 1
// baseline (2689.617 us; speedup 1.0000x reference)
//
#include <hip/hip_runtime.h>

// ---------- types / helpers ----------
typedef float f32x4 __attribute__((ext_vector_type(4)));
typedef short s16x8 __attribute__((ext_vector_type(8)));
typedef unsigned short u16x8 __attribute__((ext_vector_type(8)));
typedef unsigned short u16x4 __attribute__((ext_vector_type(4)));

__device__ __forceinline__ unsigned short f2bf(float f) {
  unsigned int u = __float_as_uint(f);
  u += 0x7FFFu + ((u >> 16) & 1u);          // round-to-nearest-even
  return (unsigned short)(u >> 16);
}
__device__ __forceinline__ float bf2f(unsigned short s) {
  return __uint_as_float(((unsigned int)s) << 16);
}

// LDS tile row stride: 40 ushorts = 80B. 80B stride => bank base rotates by 20
// banks/row: worst aliasing is 2-way (free, m136). 16B units stay aligned.
#define LROW 40

__device__ __forceinline__ void pack_store(unsigned short* dst, float4 a, float4 b) {
  u16x8 v;
  v[0] = f2bf(a.x); v[1] = f2bf(a.y); v[2] = f2bf(a.z); v[3] = f2bf(a.w);
  v[4] = f2bf(b.x); v[5] = f2bf(b.y); v[6] = f2bf(b.z); v[7] = f2bf(b.w);
  *(u16x8*)dst = v;
}

// ---------- prep: w_hh fp32 -> bf16, zero h0/c ----------
__global__ __launch_bounds__(256) void prep_kernel(
    const float4* __restrict__ whh, unsigned short* __restrict__ whhb,
    unsigned short* __restrict__ h0, float* __restrict__ c) {
  int i = blockIdx.x * 256 + threadIdx.x;           // grid = 1024 blocks
  for (int j = i; j < 1048576; j += 262144) {       // 4096*1024/4 float4s
    float4 v = whh[j];
    u16x4 o; o[0] = f2bf(v.x); o[1] = f2bf(v.y); o[2] = f2bf(v.z); o[3] = f2bf(v.w);
    *(u16x4*)&whhb[(size_t)j << 2] = o;
  }
  if (i < 32768) { h0[i] = 0; c[i] = 0.f; }         // 32*1024 state
}

// ---------- phase 1: x_gates[s*32+b][g] = emb[ids[b][s]] . w_ih[g] + bias ----------
__global__ __launch_bounds__(256) void gemm_p1(
    const int* __restrict__ ids, const float* __restrict__ emb,
    const float* __restrict__ wih, const float* __restrict__ bih,
    const float* __restrict__ bhh, unsigned short* __restrict__ xg) {
  __shared__ unsigned short As[128 * LROW];
  __shared__ unsigned short Bs[128 * LROW];
  const int tid = threadIdx.x;
  const int lane = tid & 63, wid = tid >> 6;
  const int wr = wid >> 1, wc = wid & 1;
  const int m0 = blockIdx.y << 7, n0 = blockIdx.x << 7;
  const int l15 = lane & 15, kg = lane >> 4;

  // staging descriptors: 2 passes, each thread handles one 8-float chunk
  const float* asrc[2]; const float* bsrc[2]; int ldoff[2];
#pragma unroll
  for (int p = 0; p < 2; ++p) {
    int flat = (p << 11) + (tid << 3);
    int row = flat >> 5;                 // row within 128-row tile
    int kq  = (flat >> 3) & 3;           // which 8-elem chunk of BK=32
    ldoff[p] = row * LROW + (kq << 3);
    int R = m0 + row;                    // R = s*32 + b
    int id = ids[((R & 31) << 7) + (R >> 5)];   // ids[b*128 + s]
    asrc[p] = emb + (size_t)id * 1024 + (kq << 3);
    bsrc[p] = wih + (size_t)(n0 + row) * 1024 + (kq << 3);
  }

  f32x4 acc[4][4] = {};
  const int ar = (wr << 6) + l15, br = (wc << 6) + l15;

  for (int kt = 0; kt < 1024; kt += 32) {
#pragma unroll
    for (int p = 0; p < 2; ++p) {
      float4 a0 = *(const float4*)(asrc[p] + kt);
      float4 a1 = *(const float4*)(asrc[p] + kt + 4);
      float4 b0 = *(const float4*)(bsrc[p] + kt);
      float4 b1 = *(const float4*)(bsrc[p] + kt + 4);
      pack_store(&As[ldoff[p]], a0, a1);
      pack_store(&Bs[ldoff[p]], b0, b1);
    }
    __syncthreads();
    s16x8 af[4], bf[4];
#pragma unroll
    for (int i = 0; i < 4; ++i) {
      af[i] = *(const s16x8*)&As[(ar + (i << 4)) * LROW + (kg << 3)];
      bf[i] = *(const s16x8*)&Bs[(br + (i << 4)) * LROW + (kg << 3)];
    }
#pragma unroll
    for (int i = 0; i < 4; ++i)
#pragma unroll
      for (int j = 0; j < 4; ++j)
        acc[i][j] = __builtin_amdgcn_mfma_f32_16x16x32_bf16(af[i], bf[j], acc[i][j], 0, 0, 0);
    __syncthreads();
  }

  const int rbase = m0 + (wr << 6) + ((lane >> 4) << 2);
  const int cbase = n0 + (wc << 6) + l15;
#pragma unroll
  for (int j = 0; j < 4; ++j) {
    int col = cbase + (j << 4);
    float bias = bih[col] + bhh[col];
#pragma unroll
    for (int i = 0; i < 4; ++i) {
      int row = rbase + (i << 4);
#pragma unroll
      for (int r = 0; r < 4; ++r)
        xg[(size_t)(row + r) * 4096 + col] = f2bf(acc[i][j][r] + bias);
    }
  }
}

// ---------- phase 2: one LSTM step ----------
// grid = 64 blocks; block b owns h-cols [b*16, b*16+16) for all 4 gates.
// 4 waves K-split (256 each) -> LDS reduce -> wave 0 does gate math + c/h update.
__global__ __launch_bounds__(256) void lstm_step(
    const unsigned short* __restrict__ xg,    // x_gates + s*32*4096 (bf16)
    const unsigned short* __restrict__ whh,   // bf16 [4096][1024]
    const unsigned short* __restrict__ hprev, // bf16 [32][1024]
    unsigned short* __restrict__ hnext,       // bf16 [32][1024]
    float* __restrict__ c,                    // fp32 [32][1024]
    unsigned short* __restrict__ hs) {        // hs + (s-40)*1024, or nullptr
  __shared__ float red[32 * 192];
  const int tid = threadIdx.x, lane = tid & 63, wid = tid >> 6;
  const int n0 = blockIdx.x << 4;
  const int l15 = lane & 15, kg = lane >> 4;

  f32x4 acc[2][4] = {};
  const unsigned short* ap0 = hprev + (size_t)l15 * 1024 + wid * 256 + (kg << 3);
  const unsigned short* ap1 = ap0 + 16 * 1024;
  const unsigned short* bp[4];
#pragma unroll
  for (int g = 0; g < 4; ++g)
    bp[g] = whh + (size_t)(g * 1024 + n0 + l15) * 1024 + wid * 256 + (kg << 3);

#pragma unroll 2
  for (int kk = 0; kk < 8; ++kk) {
    s16x8 a0 = *(const s16x8*)(ap0 + kk * 32);
    s16x8 a1 = *(const s16x8*)(ap1 + kk * 32);
#pragma unroll
    for (int g = 0; g < 4; ++g) {
      s16x8 bfr = *(const s16x8*)(bp[g] + kk * 32);
      acc[0][g] = __builtin_amdgcn_mfma_f32_16x16x32_bf16(a0, bfr, acc[0][g], 0, 0, 0);
      acc[1][g] = __builtin_amdgcn_mfma_f32_16x16x32_bf16(a1, bfr, acc[1][g], 0, 0, 0);
    }
  }

  if (wid) {
#pragma unroll
    for (int mi = 0; mi < 2; ++mi)
#pragma unroll
      for (int g = 0; g < 4; ++g)
#pragma unroll
        for (int r = 0; r < 4; ++r)
          red[(mi * 16 + g * 4 + r) * 192 + (wid - 1) * 64 + lane] = acc[mi][g][r];
  }
  __syncthreads();
  if (wid == 0) {
#pragma unroll
    for (int mi = 0; mi < 2; ++mi)
#pragma unroll
      for (int g = 0; g < 4; ++g)
#pragma unroll
        for (int r = 0; r < 4; ++r) {
          int idx = (mi * 16 + g * 4 + r) * 192 + lane;
          acc[mi][g][r] += red[idx] + red[idx + 64] + red[idx + 128];
        }
#pragma unroll
    for (int mi = 0; mi < 2; ++mi) {
#pragma unroll
      for (int r = 0; r < 4; ++r) {
        int row = mi * 16 + ((lane >> 4) << 2) + r;   // batch index b
        int col = n0 + l15;                           // h index
        size_t xrow = (size_t)row * 4096;
        float iv = acc[mi][0][r] + bf2f(xg[xrow + col]);
        float fv = acc[mi][1][r] + bf2f(xg[xrow + 1024 + col]);
        float gv = acc[mi][2][r] + bf2f(xg[xrow + 2048 + col]);
        float ov = acc[mi][3][r] + bf2f(xg[xrow + 3072 + col]);
        float ig = 1.f / (1.f + expf(-iv));
        float fg = 1.f / (1.f + expf(-fv));
        float og = 1.f / (1.f + expf(-ov));
        float gg = tanhf(gv);
        int ci = row * 1024 + col;
        float cn = fg * c[ci] + ig * gg;
        c[ci] = cn;
        float h = og * tanhf(cn);
        hnext[ci] = f2bf(h);
        if (hs) hs[(size_t)row * (88 * 1024) + col] = f2bf(h);
      }
    }
  }
}

// ---------- phase 3: out[r][v] = hs[r] . w_out[v] + b_out[v] ----------
__global__ __launch_bounds__(256) void gemm_p3(
    const unsigned short* __restrict__ hs, const float* __restrict__ wout,
    const float* __restrict__ bout, float* __restrict__ out) {
  __shared__ unsigned short As[128 * LROW];
  __shared__ unsigned short Bs[128 * LROW];
  const int tid = threadIdx.x;
  const int lane = tid & 63, wid = tid >> 6;
  const int wr = wid >> 1, wc = wid & 1;
  const int m0 = blockIdx.y << 7, n0 = blockIdx.x << 7;
  const int l15 = lane & 15, kg = lane >> 4;

  const unsigned short* asrc[2]; const float* bsrc[2]; int ldoff[2];
#pragma unroll
  for (int p = 0; p < 2; ++p) {
    int flat = (p << 11) + (tid << 3);
    int row = flat >> 5;
    int kq  = (flat >> 3) & 3;
    ldoff[p] = row * LROW + (kq << 3);
    asrc[p] = hs + (size_t)(m0 + row) * 1024 + (kq << 3);
    bsrc[p] = wout + (size_t)(n0 + row) * 1024 + (kq << 3);
  }

  f32x4 acc[4][4] = {};
  const int ar = (wr << 6) + l15, br = (wc << 6) + l15;

  for (int kt = 0; kt < 1024; kt += 32) {
#pragma unroll
    for (int p = 0; p < 2; ++p) {
      *(u16x8*)&As[ldoff[p]] = *(const u16x8*)(asrc[p] + kt);  // A already bf16
      float4 b0 = *(const float4*)(bsrc[p] + kt);
      float4 b1 = *(const float4*)(bsrc[p] + kt + 4);
      pack_store(&Bs[ldoff[p]], b0, b1);
    }
    __syncthreads();
    s16x8 af[4], bf[4];
#pragma unroll
    for (int i = 0; i < 4; ++i) {
      af[i] = *(const s16x8*)&As[(ar + (i << 4)) * LROW + (kg << 3)];
      bf[i] = *(const s16x8*)&Bs[(br + (i << 4)) * LROW + (kg << 3)];
    }
#pragma unroll
    for (int i = 0; i < 4; ++i)
#pragma unroll
      for (int j = 0; j < 4; ++j)
        acc[i][j] = __builtin_amdgcn_mfma_f32_16x16x32_bf16(af[i], bf[j], acc[i][j], 0, 0, 0);
    __syncthreads();
  }

  const int rbase = m0 + (wr << 6) + ((lane >> 4) << 2);
  const int cbase = n0 + (wc << 6) + l15;
#pragma unroll
  for (int j = 0; j < 4; ++j) {
    int col = cbase + (j << 4);
    float bias = bout[col];
#pragma unroll
    for (int i = 0; i < 4; ++i) {
      int row = rbase + (i << 4);
#pragma unroll
      for (int r = 0; r < 4; ++r)
        out[(size_t)(row + r) * 32000 + col] = acc[i][j][r] + bias;
    }
  }
}

// ---------- host ----------
extern "C" void kernel_launch(void* const* d_in, const int* in_sizes, int n_in,
                              void* d_out, int out_size, void* d_ws, size_t ws_size,
                              hipStream_t stream) {
  (void)in_sizes; (void)n_in; (void)out_size; (void)ws_size;
  const int*   ids  = (const int*)d_in[0];
  const float* emb  = (const float*)d_in[1];
  const float* wih  = (const float*)d_in[2];
  const float* whh  = (const float*)d_in[3];
  const float* bih  = (const float*)d_in[4];
  const float* bhh  = (const float*)d_in[5];
  const float* wout = (const float*)d_in[6];
  const float* bout = (const float*)d_in[7];
  float* out = (float*)d_out;
  char* ws = (char*)d_ws;

  // ws layout (total ~45.8 MiB)
  unsigned short* whhb = (unsigned short*)(ws);               //  8,388,608 B
  unsigned short* xg   = (unsigned short*)(ws + 8388608);     // 33,554,432 B
  unsigned short* hsb  = (unsigned short*)(ws + 41943040);    //  5,767,168 B
  unsigned short* h0   = (unsigned short*)(ws + 47710208);    //     65,536 B
  unsigned short* h1   = (unsigned short*)(ws + 47775744);    //     65,536 B
  float*          cst  = (float*)        (ws + 47841280);     //    131,072 B

  prep_kernel<<<1024, 256, 0, stream>>>((const float4*)whh, whhb, h0, cst);

  dim3 g1(32, 32);
  gemm_p1<<<g1, 256, 0, stream>>>(ids, emb, wih, bih, bhh, xg);

  for (int s = 0; s < 128; ++s) {
    unsigned short* hp = (s & 1) ? h1 : h0;
    unsigned short* hn = (s & 1) ? h0 : h1;
    unsigned short* hso = (s >= 40) ? (hsb + (size_t)(s - 40) * 1024) : (unsigned short*)nullptr;
    lstm_step<<<64, 256, 0, stream>>>(xg + (size_t)s * 131072, whhb, hp, hn, cst, hso);
  }

  dim3 g3(250, 22);
  gemm_p3<<<g3, 256, 0, stream>>>(hsb, wout, bout, out);
}